// Round 11
// baseline (52668.237 us; speedup 1.0000x reference)
//
#include <hip/hip_runtime.h>
#include <stdint.h>

#define N_SITES 144
#define NHID    256
#define NSAMP   1024
#define MB      4           // samples per block
#define TPB     1024        // 16 waves: 12 A-waves (768 cols) + 4 G-waves (256 units)
#define NAW     12          // A-waves
#define PARTITIONABLE 1

#define LD(p)    __hip_atomic_load((p), __ATOMIC_ACQUIRE, __HIP_MEMORY_SCOPE_WORKGROUP)
#define ST(p, v) __hip_atomic_store((p), (v), __ATOMIC_RELEASE, __HIP_MEMORY_SCOPE_WORKGROUP)

__device__ __forceinline__ uint32_t rotl32(uint32_t v, uint32_t r) {
    return (v << r) | (v >> (32u - r));
}

// JAX threefry2x32: 20 rounds, key injections every 4
__device__ __forceinline__ void threefry(uint32_t k0, uint32_t k1,
                                         uint32_t x0, uint32_t x1,
                                         uint32_t& o0, uint32_t& o1) {
    uint32_t ks0 = k0, ks1 = k1, ks2 = k0 ^ k1 ^ 0x1BD11BDAu;
    x0 += ks0; x1 += ks1;
#define RG4(a,b,c,d) \
    x0 += x1; x1 = rotl32(x1,a); x1 ^= x0; \
    x0 += x1; x1 = rotl32(x1,b); x1 ^= x0; \
    x0 += x1; x1 = rotl32(x1,c); x1 ^= x0; \
    x0 += x1; x1 = rotl32(x1,d); x1 ^= x0;
    RG4(13,15,26,6)  x0 += ks1; x1 += ks2 + 1u;
    RG4(17,29,16,24) x0 += ks2; x1 += ks0 + 2u;
    RG4(13,15,26,6)  x0 += ks0; x1 += ks1 + 3u;
    RG4(17,29,16,24) x0 += ks1; x1 += ks2 + 4u;
    RG4(13,15,26,6)  x0 += ks2; x1 += ks0 + 5u;
#undef RG4
    o0 = x0; o1 = x1;
}

__device__ __forceinline__ float gumbel_from_bits(uint32_t bits) {
#pragma clang fp contract(off)
    const float TINY = 1.17549435e-38f;          // finfo(f32).tiny
    uint32_t fb = (bits >> 9) | 0x3f800000u;
    float u = __uint_as_float(fb) - 1.0f;        // [0,1)
    u = u * (1.0f - TINY) + TINY;                // matches JAX uniform()
    u = fmaxf(TINY, u);
    return -logf(-logf(u));
}

// One-time prep (R8-verified): recQ[k/4][col][j] = rec[4*(k/4)+j][col].
__global__ void repack_rec(const float* __restrict__ rec,
                           float* __restrict__ recQ) {
    const int col = blockIdx.x;           // 0..767
    const int k   = threadIdx.x;          // 0..255
    recQ[((size_t)(k >> 2) * 768 + col) * 4 + (k & 3)] = rec[(size_t)k * 768 + col];
}

template <bool QUAD>
__global__ __launch_bounds__(TPB, 1)
void rnn_sample_kernel(const float* __restrict__ kern,   // [2,768]
                       const float* __restrict__ rec,    // QUAD ? recQ[64][768][4] : rec[256][768]
                       const float* __restrict__ bias,   // [2,768]
                       const float* __restrict__ dw,     // [256,2]
                       const float* __restrict__ db,     // [2]
                       float* __restrict__ out)          // samples[1024*144] ++ logP[1024]
{
    const int t    = threadIdx.x;
    const int blk  = blockIdx.x;
    const int b0   = blk * MB;
    const int wid  = t >> 6;
    const int lane = t & 63;

    // Producer-consumer pipeline: NO barriers in the steady loop.
    __shared__ float4   hbuf[2][NHID];      // double-buffered h (8 KB): A(n) reads [n&1]
    __shared__ float    pacc[MB][768];      // phase-A partials (12 KB)
    __shared__ uint32_t keyA[N_SITES], keyB[N_SITES];
    __shared__ float    glds[N_SITES][MB][2];  // precomputed gumbels (4.6 KB)
    __shared__ float    wred[MB][4][2];     // dense partials [sample][group][{a,b}]
    __shared__ int      sPrev[MB];
    // monotonic step-counter flags (never reset; value encodes progress)
    __shared__ int hflag[4];       // h states available for k-tile T (init 1 = state 0)
    __shared__ int paccflag[NAW];  // pacc steps produced by A-wave w
    __shared__ int gdone[4];       // pacc steps consumed by G-wave g
    __shared__ int wflag[4];       // wred steps produced by G-wave g
    __shared__ int sflag;          // phase-D steps completed

    // ---- init ----
    if (t < NHID) { hbuf[0][t] = make_float4(0.f,0.f,0.f,0.f); hbuf[1][t] = make_float4(0.f,0.f,0.f,0.f); }
    if (t < MB)  sPrev[t] = -1;
    if (t < 4)   { hflag[t] = 1; gdone[t] = 0; wflag[t] = 0; }
    if (t < NAW) paccflag[t] = 0;
    if (t == 0)  sflag = 0;
    if (t < N_SITES) {
        uint32_t o0, o1;
        threefry(0u, 42u, 0u, (uint32_t)t, o0, o1);   // foldlike split: counter = n
        keyA[t] = o0; keyB[t] = o1;
    }
    __syncthreads();
    if (t < N_SITES * MB) {       // gumbel precompute (R6/R8-verified, bit-identical)
        const int n = t >> 2, m = t & 3;
        uint32_t o0a, o1a, o0b, o1b;
        const uint32_t fbase = 2u * (uint32_t)(b0 + m);
        threefry(keyA[n], keyB[n], 0u, fbase,      o0a, o1a);
        threefry(keyA[n], keyB[n], 0u, fbase + 1u, o0b, o1b);
        glds[n][m][0] = gumbel_from_bits(o0a ^ o1a);
        glds[n][m][1] = gumbel_from_bits(o0b ^ o1b);
    }
    __syncthreads();   // last barrier; steady loop is flag-driven

    if (wid < NAW) {
        // ================= A-waves: one column per thread, 768 cols =================
        if (QUAD) {
            const float4* rq = reinterpret_cast<const float4*>(rec) + t;
            // 8-deep weight prefetch, two named banks of 4 (compile-time indices
            // only -- rule #20). R10's VGPR=32 showed the acquire spins fenced the
            // compiler's own pipelining to ~2 deep; explicit rotation restores
            // R8's depth. Loads are program-order BEFORE the flag spins, so they
            // stay in flight across the acquire. Prefetch wraps mod 64: the last
            // chunks of step n issue groups 0..7 for step n+1, which fly during
            // the pacc-store / gate-phase handoff gap.
            float4 wA = rq[0 * 768], wB = rq[1 * 768], wC = rq[2 * 768], wD = rq[3 * 768];
            float4 xA = rq[4 * 768], xB = rq[5 * 768], xC = rq[6 * 768], xD = rq[7 * 768];
            for (int n = 0; n < N_SITES; ++n) {
                const float4* hb = hbuf[n & 1];
                float a0 = 0.f, a1 = 0.f, a2 = 0.f, a3 = 0.f;
#pragma unroll
                for (int T = 0; T < 4; ++T) {
                    while (LD(&hflag[T]) < n + 1) {}   // h-tile T of state n ready?
#pragma unroll
                    for (int q = 0; q < 4; ++q) {
                        const int c  = 4 * T + q;      // chunk: groups 4c..4c+3 (compile-time)
                        const float4 uA = wA, uB = wB, uC = wC, uD = wD;
                        wA = xA; wB = xB; wC = xC; wD = xD;
                        {   // issue next 4 loads (T14 issue-early, before FMAs)
                            const int gn = (4 * c + 8) & 63;
                            xA = rq[(size_t)(gn + 0) * 768];
                            xB = rq[(size_t)(gn + 1) * 768];
                            xC = rq[(size_t)(gn + 2) * 768];
                            xD = rq[(size_t)(gn + 3) * 768];
                        }
#define GSTEP(W, G) { \
                        float4 h4 = hb[4 * (G) + 0]; \
                        a0 = fmaf(h4.x, (W).x, a0); a1 = fmaf(h4.y, (W).x, a1); \
                        a2 = fmaf(h4.z, (W).x, a2); a3 = fmaf(h4.w, (W).x, a3); \
                        h4 = hb[4 * (G) + 1]; \
                        a0 = fmaf(h4.x, (W).y, a0); a1 = fmaf(h4.y, (W).y, a1); \
                        a2 = fmaf(h4.z, (W).y, a2); a3 = fmaf(h4.w, (W).y, a3); \
                        h4 = hb[4 * (G) + 2]; \
                        a0 = fmaf(h4.x, (W).z, a0); a1 = fmaf(h4.y, (W).z, a1); \
                        a2 = fmaf(h4.z, (W).z, a2); a3 = fmaf(h4.w, (W).z, a3); \
                        h4 = hb[4 * (G) + 3]; \
                        a0 = fmaf(h4.x, (W).w, a0); a1 = fmaf(h4.y, (W).w, a1); \
                        a2 = fmaf(h4.z, (W).w, a2); a3 = fmaf(h4.w, (W).w, a3); }
                        GSTEP(uA, 4 * c + 0)
                        GSTEP(uB, 4 * c + 1)
                        GSTEP(uC, 4 * c + 2)
                        GSTEP(uD, 4 * c + 3)
#undef GSTEP
                    }
                }
                // WAR guard: G-wave (wid&3) must have consumed pacc(n-1)
                while (LD(&gdone[wid & 3]) < n) {}
                pacc[0][t] = a0; pacc[1][t] = a1; pacc[2][t] = a2; pacc[3][t] = a3;
                if (lane == 0) ST(&paccflag[wid], n + 1);   // release: drains wave's ds writes
            }
        } else {
            const float* rp = rec + t;
            for (int n = 0; n < N_SITES; ++n) {
                const float4* hb = hbuf[n & 1];
                float a0 = 0.f, a1 = 0.f, a2 = 0.f, a3 = 0.f;
                for (int T = 0; T < 4; ++T) {
                    while (LD(&hflag[T]) < n + 1) {}
#pragma unroll 8
                    for (int k = 64 * T; k < 64 * T + 64; ++k) {
                        float4 h4 = hb[k];
                        float w  = rp[(size_t)k * 768];
                        a0 = fmaf(h4.x, w, a0); a1 = fmaf(h4.y, w, a1);
                        a2 = fmaf(h4.z, w, a2); a3 = fmaf(h4.w, w, a3);
                    }
                }
                while (LD(&gdone[wid & 3]) < n) {}
                pacc[0][t] = a0; pacc[1][t] = a1; pacc[2][t] = a2; pacc[3][t] = a3;
                if (lane == 0) ST(&paccflag[wid], n + 1);
            }
        }
    } else {
        // ================= G-waves: gates/h/dense/D for 64 units each =================
        const int g = wid - NAW;              // 0..3
        const int u = (g << 6) | lane;        // unit id
        const float kz0 = kern[u];        const float kr0 = kern[u + 256];       const float kn0 = kern[u + 512];
        const float kz1 = kern[768 + u];  const float kr1 = kern[768 + u + 256]; const float kn1 = kern[768 + u + 512];
        const float b0z = bias[u];        const float b0r = bias[u + 256];       const float b0n = bias[u + 512];
        const float b1z = bias[768 + u];  const float b1r = bias[768 + u + 256]; const float b1n = bias[768 + u + 512];
        const float dwa = dw[2 * u];      const float dwb = dw[2 * u + 1];
        const float dba = db[0];          const float dbb = db[1];
        float lgP0 = 0.f, lgP1 = 0.f, lgP2 = 0.f, lgP3 = 0.f;   // D-thread only

        for (int n = 0; n < N_SITES; ++n) {
            while (LD(&sflag) < n) __builtin_amdgcn_s_sleep(1);      // D(n-1) done
            const int sp0 = sPrev[0], sp1 = sPrev[1], sp2 = sPrev[2], sp3 = sPrev[3];
            while (LD(&paccflag[g    ]) < n + 1) __builtin_amdgcn_s_sleep(1);  // z cols
            while (LD(&paccflag[g + 4]) < n + 1) __builtin_amdgcn_s_sleep(1);  // r cols
            while (LD(&paccflag[g + 8]) < n + 1) __builtin_amdgcn_s_sleep(1);  // n cols

            const float4 ho = hbuf[n & 1][u];
            const float hold[MB] = { ho.x, ho.y, ho.z, ho.w };
            const int   spA[MB]  = { sp0, sp1, sp2, sp3 };
            float hnew[MB];
            {
#pragma clang fp contract(off)
#pragma unroll
                for (int m = 0; m < MB; ++m) {
                    const int sp = spA[m];
                    float xz = (sp == 0) ? kz0 : ((sp == 1) ? kz1 : 0.f);
                    float xr = (sp == 0) ? kr0 : ((sp == 1) ? kr1 : 0.f);
                    float xh = (sp == 0) ? kn0 : ((sp == 1) ? kn1 : 0.f);
                    xz = xz + b0z;  xr = xr + b0r;  xh = xh + b0n;
                    const float hz = pacc[m][u]       + b1z;
                    const float hr = pacc[m][u + 256] + b1r;
                    const float hn = pacc[m][u + 512] + b1n;
                    const float z = 1.0f / (1.0f + expf(-(xz + hz)));
                    const float r = 1.0f / (1.0f + expf(-(xr + hr)));
                    const float rhn = r * hn;
                    const float hh = tanhf(xh + rhn);
                    hnew[m] = z * hold[m] + (1.0f - z) * hh;
                }
            }
            if (lane == 0) ST(&gdone[g], n + 1);           // pacc consumed; A may overwrite
            hbuf[(n + 1) & 1][u] = make_float4(hnew[0], hnew[1], hnew[2], hnew[3]);
            if (lane == 0) ST(&hflag[g], n + 2);           // h-tile g of state n+1 ready

            // dense partials: same 64-lane butterfly, same lane<->unit map as R6/R8
#pragma unroll
            for (int m = 0; m < MB; ++m) {
                float va = hnew[m] * dwa;
                float vb = hnew[m] * dwb;
#pragma unroll
                for (int off = 32; off > 0; off >>= 1) {
                    va += __shfl_xor(va, off, 64);
                    vb += __shfl_xor(vb, off, 64);
                }
                if (lane == 0) { wred[m][g][0] = va; wred[m][g][1] = vb; }
            }
            if (lane == 0) ST(&wflag[g], n + 1);

            if (g == 0 && lane == 0) {
                // ---- phase D (one thread): same summation order as verified ----
                while (LD(&wflag[0]) < n + 1) {}
                while (LD(&wflag[1]) < n + 1) {}
                while (LD(&wflag[2]) < n + 1) {}
                while (LD(&wflag[3]) < n + 1) {}
#pragma unroll
                for (int m = 0; m < MB; ++m) {
#pragma clang fp contract(off)
                    const float l0r = wred[m][0][0] + wred[m][1][0] + wred[m][2][0] + wred[m][3][0];
                    const float l1r = wred[m][0][1] + wred[m][1][1] + wred[m][2][1] + wred[m][3][1];
                    const float g0 = glds[n][m][0];
                    const float g1 = glds[n][m][1];
                    const float l0 = l0r + dba;
                    const float l1 = l1r + dbb;
                    const float mx = fmaxf(l0, l1);
                    const float e0 = expf(l0 - mx), e1 = expf(l1 - mx);
                    const float den = e0 + e1;
                    const float lp0 = logf(1e-10f + e0 / den);
                    const float lp1 = logf(1e-10f + e1 / den);
                    const float v0 = g0 + lp0;
                    const float v1 = g1 + lp1;
                    const int s = (v1 > v0) ? 1 : 0;   // argmax, first-index tie-break
                    sPrev[m] = s;
                    const float d = s ? lp1 : lp0;
                    if (m == 0) lgP0 += d; else if (m == 1) lgP1 += d;
                    else if (m == 2) lgP2 += d; else lgP3 += d;
                    out[(size_t)(b0 + m) * N_SITES + n] = (float)s;
                }
                ST(&sflag, n + 1);
            }
        }
        if (g == 0 && lane == 0) {
            out[(size_t)NSAMP * N_SITES + b0 + 0] = lgP0;
            out[(size_t)NSAMP * N_SITES + b0 + 1] = lgP1;
            out[(size_t)NSAMP * N_SITES + b0 + 2] = lgP2;
            out[(size_t)NSAMP * N_SITES + b0 + 3] = lgP3;
        }
    }
}

extern "C" void kernel_launch(void* const* d_in, const int* in_sizes, int n_in,
                              void* d_out, int out_size, void* d_ws, size_t ws_size,
                              hipStream_t stream) {
    (void)in_sizes; (void)n_in; (void)out_size;
    const float* kern = (const float*)d_in[0];
    const float* rec  = (const float*)d_in[1];
    const float* bias = (const float*)d_in[2];
    const float* dwp  = (const float*)d_in[3];
    const float* dbp  = (const float*)d_in[4];
    float* out = (float*)d_out;

    const size_t needQ = sizeof(float) * (size_t)NHID * 768;   // 786 KB
    if (d_ws != nullptr && ws_size >= needQ) {
        float* recQ = (float*)d_ws;
        repack_rec<<<768, NHID, 0, stream>>>(rec, recQ);
        rnn_sample_kernel<true><<<NSAMP / MB, TPB, 0, stream>>>(kern, recQ, bias, dwp, dbp, out);
    } else {
        rnn_sample_kernel<false><<<NSAMP / MB, TPB, 0, stream>>>(kern, rec, bias, dwp, dbp, out);
    }
}

// Round 12
// 1668.193 us; speedup vs baseline: 31.5720x; 31.5720x over previous
//
#include <hip/hip_runtime.h>
#include <stdint.h>

#define N_SITES 144
#define NHID    256
#define NSAMP   1024
#define MB      4          // samples per block
#define TPB     768        // one gate-column per thread; 12 waves = 3 waves/SIMD
#define PARTITIONABLE 1

__device__ __forceinline__ uint32_t rotl32(uint32_t v, uint32_t r) {
    return (v << r) | (v >> (32u - r));
}

// JAX threefry2x32: 20 rounds, key injections every 4
__device__ __forceinline__ void threefry(uint32_t k0, uint32_t k1,
                                         uint32_t x0, uint32_t x1,
                                         uint32_t& o0, uint32_t& o1) {
    uint32_t ks0 = k0, ks1 = k1, ks2 = k0 ^ k1 ^ 0x1BD11BDAu;
    x0 += ks0; x1 += ks1;
#define RG4(a,b,c,d) \
    x0 += x1; x1 = rotl32(x1,a); x1 ^= x0; \
    x0 += x1; x1 = rotl32(x1,b); x1 ^= x0; \
    x0 += x1; x1 = rotl32(x1,c); x1 ^= x0; \
    x0 += x1; x1 = rotl32(x1,d); x1 ^= x0;
    RG4(13,15,26,6)  x0 += ks1; x1 += ks2 + 1u;
    RG4(17,29,16,24) x0 += ks2; x1 += ks0 + 2u;
    RG4(13,15,26,6)  x0 += ks0; x1 += ks1 + 3u;
    RG4(17,29,16,24) x0 += ks1; x1 += ks2 + 4u;
    RG4(13,15,26,6)  x0 += ks2; x1 += ks0 + 5u;
#undef RG4
    o0 = x0; o1 = x1;
}

__device__ __forceinline__ float gumbel_from_bits(uint32_t bits) {
#pragma clang fp contract(off)
    const float TINY = 1.17549435e-38f;          // finfo(f32).tiny
    uint32_t fb = (bits >> 9) | 0x3f800000u;
    float u = __uint_as_float(fb) - 1.0f;        // [0,1)
    u = u * (1.0f - TINY) + TINY;                // matches JAX uniform()
    u = fmaxf(TINY, u);
    return -logf(-logf(u));
}

// One-time prep (R8-verified): recQ[k/4][col][j] = rec[4*(k/4)+j][col].
// Pure copy -> bit-exact. 16 B/lane loads that are ALSO wave-coalesced.
__global__ void repack_rec(const float* __restrict__ rec,
                           float* __restrict__ recQ) {
    const int col = blockIdx.x;           // 0..767
    const int k   = threadIdx.x;          // 0..255
    recQ[((size_t)(k >> 2) * TPB + col) * 4 + (k & 3)] = rec[(size_t)k * TPB + col];
}

// 16 FMAs for k-group G (k = 4G..4G+3) with weight quad W. Ascending-k,
// single-accumulator chain -> bit-exact vs all verified versions.
#define GRSTEP(W, G) { \
    float4 h4 = hs4[4 * (G) + 0]; \
    a0 = fmaf(h4.x, (W).x, a0); a1 = fmaf(h4.y, (W).x, a1); \
    a2 = fmaf(h4.z, (W).x, a2); a3 = fmaf(h4.w, (W).x, a3); \
    h4 = hs4[4 * (G) + 1]; \
    a0 = fmaf(h4.x, (W).y, a0); a1 = fmaf(h4.y, (W).y, a1); \
    a2 = fmaf(h4.z, (W).y, a2); a3 = fmaf(h4.w, (W).y, a3); \
    h4 = hs4[4 * (G) + 2]; \
    a0 = fmaf(h4.x, (W).z, a0); a1 = fmaf(h4.y, (W).z, a1); \
    a2 = fmaf(h4.z, (W).z, a2); a3 = fmaf(h4.w, (W).z, a3); \
    h4 = hs4[4 * (G) + 3]; \
    a0 = fmaf(h4.x, (W).w, a0); a1 = fmaf(h4.y, (W).w, a1); \
    a2 = fmaf(h4.z, (W).w, a2); a3 = fmaf(h4.w, (W).w, a3); }

template <bool QUAD>
__global__ __launch_bounds__(TPB, 1)
void rnn_sample_kernel(const float* __restrict__ kern,   // [2,768]
                       const float* __restrict__ rec,    // QUAD ? recQ[64][768][4] : rec[256][768]
                       const float* __restrict__ bias,   // [2,768]
                       const float* __restrict__ dw,     // [256,2]
                       const float* __restrict__ db,     // [2]
                       float* __restrict__ out)          // samples[1024*144] ++ logP[1024]
{
    const int t    = threadIdx.x;          // 0..767 == gate column index
    const int blk  = blockIdx.x;
    const int b0   = blk * MB;
    const int lane = t & 63;
    const int u    = t & 255;              // hidden-unit id for phase B/C
    const int m1   = t >> 8;               // first-pass sample id (0,1,2)

    __shared__ float4   hs4[NHID];          // h[k] packed over 4 samples (4 KB)
    __shared__ float    pacc[MB][TPB];      // phase-A partials, [sample][col] (12 KB)
    __shared__ uint32_t keyA[N_SITES], keyB[N_SITES];
    __shared__ float    glds[N_SITES][MB][2];  // precomputed gumbels (4.6 KB)
    __shared__ float    wred[MB][4][2];     // dense partials [sample][group][{a,b}]
    __shared__ int      sPrev[MB];

    // ---- per-thread constants: unit-u gate triples (all 768 threads) ----
    const float kz0 = kern[u];        const float kr0 = kern[u + 256];  const float kn0 = kern[u + 512];
    const float kz1 = kern[768 + u];  const float kr1 = kern[768 + u + 256]; const float kn1 = kern[768 + u + 512];
    const float b0z = bias[u];        const float b0r = bias[u + 256];  const float b0n = bias[u + 512];
    const float b1z = bias[768 + u];  const float b1r = bias[768 + u + 256]; const float b1n = bias[768 + u + 512];
    const float dwa = dw[2 * u];      const float dwb = dw[2 * u + 1];
    const float dba = db[0];          const float dbb = db[1];
    float lgPr = 0.f;                                 // logP (threads 0..3)
    if (t < NHID) hs4[t] = make_float4(0.f, 0.f, 0.f, 0.f);
    if (t < MB) sPrev[t] = -1;
    if (t < N_SITES) {
        uint32_t o0, o1;
        threefry(0u, 42u, 0u, (uint32_t)t, o0, o1);   // foldlike split: counter = n
        keyA[t] = o0; keyB[t] = o1;
    }
    __syncthreads();

    // ---- gumbel precompute: data-independent, hoisted out of the step loop
    //      (same threefry inputs as the in-loop version -> bit-identical) ----
    if (t < N_SITES * MB) {
        const int n = t >> 2, m = t & 3;
        uint32_t o0a, o1a, o0b, o1b;
        const uint32_t fbase = 2u * (uint32_t)(b0 + m);
        threefry(keyA[n], keyB[n], 0u, fbase,      o0a, o1a);
        threefry(keyA[n], keyB[n], 0u, fbase + 1u, o0b, o1b);
        glds[n][m][0] = gumbel_from_bits(o0a ^ o1a);
        glds[n][m][1] = gumbel_from_bits(o0b ^ o1b);
    }
    __syncthreads();

    // ---- cross-step weight prefetch: groups 0..7 of the next step held in 8
    //      named float4s (32 VGPRs, compile-time indices). ONE issue point
    //      (end of phase A) and ONE consume point (start of next phase A),
    //      no fences between issue and the B1 drain -> no rotation across
    //      acquire fences (R11's spill cause). B1's vmcnt(0) completes them;
    //      their 98 KB of L1 fill transits during the tail instead of
    //      serializing at the head of the next phase A. ----
    const float4* rq = nullptr;
    float4 pA, pB, pC, pD, pE, pF, pG, pH;
    if (QUAD) {
        rq = reinterpret_cast<const float4*>(rec) + t;
        pA = rq[0 * TPB]; pB = rq[1 * TPB]; pC = rq[2 * TPB]; pD = rq[3 * TPB];
        pE = rq[4 * TPB]; pF = rq[5 * TPB]; pG = rq[6 * TPB]; pH = rq[7 * TPB];
    }

    for (int n = 0; n < N_SITES; ++n) {
        // ---- phase A: one column per thread, single-accumulator ascending
        //      k=0..255 chain (bit-exact). Groups 0..7 from prefetch regs,
        //      8..63 streamed (unroll 8 -> R8's proven in-flight depth). ----
        float a0 = 0.f, a1 = 0.f, a2 = 0.f, a3 = 0.f;
        if (QUAD) {
            GRSTEP(pA, 0) GRSTEP(pB, 1) GRSTEP(pC, 2) GRSTEP(pD, 3)
            GRSTEP(pE, 4) GRSTEP(pF, 5) GRSTEP(pG, 6) GRSTEP(pH, 7)
#pragma unroll 8
            for (int g = 8; g < 64; ++g) {
                const float4 w = rq[(size_t)g * TPB];   // k = 4g..4g+3 of column t
                GRSTEP(w, g)
            }
            // refill for step n+1 (issued before B1; completes at B1's vmcnt
            // drain; L1 fill overlaps the tail). Last-iter refill is harmless.
            pA = rq[0 * TPB]; pB = rq[1 * TPB]; pC = rq[2 * TPB]; pD = rq[3 * TPB];
            pE = rq[4 * TPB]; pF = rq[5 * TPB]; pG = rq[6 * TPB]; pH = rq[7 * TPB];
        } else {
            const float* rp = rec + t;
#pragma unroll 8
            for (int k = 0; k < NHID; ++k) {
                float4 h4 = hs4[k];          // broadcast ds_read_b128
                float w  = rp[0];
                rp += TPB;
                a0 = fmaf(h4.x, w, a0);
                a1 = fmaf(h4.y, w, a1);
                a2 = fmaf(h4.z, w, a2);
                a3 = fmaf(h4.w, w, a3);
            }
        }
        pacc[0][t] = a0; pacc[1][t] = a1; pacc[2][t] = a2; pacc[3][t] = a3;
        __syncthreads();   // B1: pacc ready; all hs4 reads complete; prefetch landed

        // ---- phases B+C spread over all 12 waves: 1024 (m,unit) gate tasks.
        //      (R6/R8-verbatim, verified bit-exact) ----
#pragma unroll
        for (int pass = 0; pass < 2; ++pass) {
            const int m = (pass == 0) ? m1 : 3;
            if (pass == 1 && t >= NHID) break;
            float hnew;
            {
#pragma clang fp contract(off)
                const int sp = sPrev[m];
                float xz = (sp == 0) ? kz0 : ((sp == 1) ? kz1 : 0.f);
                float xr = (sp == 0) ? kr0 : ((sp == 1) ? kr1 : 0.f);
                float xh = (sp == 0) ? kn0 : ((sp == 1) ? kn1 : 0.f);
                xz = xz + b0z;  xr = xr + b0r;  xh = xh + b0n;
                const float hz = pacc[m][u]       + b1z;
                const float hr = pacc[m][u + 256] + b1r;
                const float hn = pacc[m][u + 512] + b1n;
                const float z = 1.0f / (1.0f + expf(-(xz + hz)));
                const float r = 1.0f / (1.0f + expf(-(xr + hr)));
                const float rhn = r * hn;
                const float hh = tanhf(xh + rhn);
                const float hold = ((const float*)&hs4[u])[m];   // component m only
                hnew = z * hold + (1.0f - z) * hh;
                ((float*)&hs4[u])[m] = hnew;                     // ds_write_b32
            }
            // dense logits partial (h @ dense_w): butterfly over 64 lanes,
            // group g = u>>6 reproduces the old per-wave partial exactly.
            float va = hnew * dwa;
            float vb = hnew * dwb;
#pragma unroll
            for (int off = 32; off > 0; off >>= 1) {
                va += __shfl_xor(va, off, 64);
                vb += __shfl_xor(vb, off, 64);
            }
            if (lane == 0) { wred[m][u >> 6][0] = va; wred[m][u >> 6][1] = vb; }
        }
        __syncthreads();   // B2: wred + hs4 ready

        // ---- phase D: logits + categorical + logP (4 threads, gumbels precomputed) ----
        if (t < MB) {
            const int m = t;
            // same summation order as the verified kernel: g0+g1+g2+g3, then bias
            float l0 = wred[m][0][0] + wred[m][1][0] + wred[m][2][0] + wred[m][3][0];
            float l1 = wred[m][0][1] + wred[m][1][1] + wred[m][2][1] + wred[m][3][1];
            const float g0 = glds[n][m][0];
            const float g1 = glds[n][m][1];
            {
#pragma clang fp contract(off)
                l0 = l0 + dba;
                l1 = l1 + dbb;
                const float mx = fmaxf(l0, l1);
                const float e0 = expf(l0 - mx), e1 = expf(l1 - mx);
                const float den = e0 + e1;
                const float lp0 = logf(1e-10f + e0 / den);
                const float lp1 = logf(1e-10f + e1 / den);
                const float v0 = g0 + lp0;
                const float v1 = g1 + lp1;
                const int s = (v1 > v0) ? 1 : 0;   // argmax, first-index tie-break
                sPrev[m] = s;
                lgPr = lgPr + (s ? lp1 : lp0);
                out[(size_t)(b0 + m) * N_SITES + n] = (float)s;
            }
        }
        // No third barrier (verified R4-R8): phase D writes only
        // sPrev/out/lgPr(reg); next-step readers of sPrev are behind B1(n+1);
        // wred(n+1)/pacc(n+1) writes are behind B1(n+1) as well.
    }

    if (t < MB) out[(size_t)NSAMP * N_SITES + (b0 + t)] = lgPr;
}

extern "C" void kernel_launch(void* const* d_in, const int* in_sizes, int n_in,
                              void* d_out, int out_size, void* d_ws, size_t ws_size,
                              hipStream_t stream) {
    (void)in_sizes; (void)n_in; (void)out_size;
    const float* kern = (const float*)d_in[0];
    const float* rec  = (const float*)d_in[1];
    const float* bias = (const float*)d_in[2];
    const float* dwp  = (const float*)d_in[3];
    const float* dbp  = (const float*)d_in[4];
    float* out = (float*)d_out;

    const size_t needQ = sizeof(float) * (size_t)NHID * TPB;   // 786 KB
    if (d_ws != nullptr && ws_size >= needQ) {
        float* recQ = (float*)d_ws;
        repack_rec<<<TPB, NHID, 0, stream>>>(rec, recQ);
        rnn_sample_kernel<true><<<NSAMP / MB, TPB, 0, stream>>>(kern, recQ, bias, dwp, dbp, out);
    } else {
        rnn_sample_kernel<false><<<NSAMP / MB, TPB, 0, stream>>>(kern, rec, bias, dwp, dbp, out);
    }
}

// Round 13
// 1314.126 us; speedup vs baseline: 40.0785x; 1.2694x over previous
//
#include <hip/hip_runtime.h>
#include <stdint.h>

#define N_SITES 144
#define NHID    256
#define NSAMP   1024
#define MB      4          // samples per block
#define TPB     768        // one gate-column per thread; 12 waves = 3 waves/SIMD
#define PARTITIONABLE 1

typedef float f32x4 __attribute__((ext_vector_type(4)));

__device__ __forceinline__ uint32_t rotl32(uint32_t v, uint32_t r) {
    return (v << r) | (v >> (32u - r));
}

// JAX threefry2x32: 20 rounds, key injections every 4
__device__ __forceinline__ void threefry(uint32_t k0, uint32_t k1,
                                         uint32_t x0, uint32_t x1,
                                         uint32_t& o0, uint32_t& o1) {
    uint32_t ks0 = k0, ks1 = k1, ks2 = k0 ^ k1 ^ 0x1BD11BDAu;
    x0 += ks0; x1 += ks1;
#define RG4(a,b,c,d) \
    x0 += x1; x1 = rotl32(x1,a); x1 ^= x0; \
    x0 += x1; x1 = rotl32(x1,b); x1 ^= x0; \
    x0 += x1; x1 = rotl32(x1,c); x1 ^= x0; \
    x0 += x1; x1 = rotl32(x1,d); x1 ^= x0;
    RG4(13,15,26,6)  x0 += ks1; x1 += ks2 + 1u;
    RG4(17,29,16,24) x0 += ks2; x1 += ks0 + 2u;
    RG4(13,15,26,6)  x0 += ks0; x1 += ks1 + 3u;
    RG4(17,29,16,24) x0 += ks1; x1 += ks2 + 4u;
    RG4(13,15,26,6)  x0 += ks2; x1 += ks0 + 5u;
#undef RG4
    o0 = x0; o1 = x1;
}

__device__ __forceinline__ float gumbel_from_bits(uint32_t bits) {
#pragma clang fp contract(off)
    const float TINY = 1.17549435e-38f;          // finfo(f32).tiny
    uint32_t fb = (bits >> 9) | 0x3f800000u;
    float u = __uint_as_float(fb) - 1.0f;        // [0,1)
    u = u * (1.0f - TINY) + TINY;                // matches JAX uniform()
    u = fmaxf(TINY, u);
    return -logf(-logf(u));
}

// One-time prep (R8-verified): recQ[k/4][col][j] = rec[4*(k/4)+j][col].
// Pure copy -> bit-exact. 16 B/lane loads that are ALSO wave-coalesced.
__global__ void repack_rec(const float* __restrict__ rec,
                           float* __restrict__ recQ) {
    const int col = blockIdx.x;           // 0..767
    const int k   = threadIdx.x;          // 0..255
    recQ[((size_t)(k >> 2) * TPB + col) * 4 + (k & 3)] = rec[(size_t)k * TPB + col];
}

template <bool QUAD>
__global__ __launch_bounds__(TPB, 1)
void rnn_sample_kernel(const float* __restrict__ kern,   // [2,768]
                       const float* __restrict__ rec,    // QUAD ? recQ[64][768][4] : rec[256][768]
                       const float* __restrict__ bias,   // [2,768]
                       const float* __restrict__ dw,     // [256,2]
                       const float* __restrict__ db,     // [2]
                       float* __restrict__ out)          // samples[1024*144] ++ logP[1024]
{
    const int t    = threadIdx.x;          // 0..767 == gate column index
    const int blk  = blockIdx.x;
    const int b0   = blk * MB;
    const int lane = t & 63;
    const int u    = t & 255;              // hidden-unit id for phase B/C
    const int m1   = t >> 8;               // first-pass sample id (0,1,2)

    __shared__ float4   hs4[NHID];          // h[k] packed over 4 samples (4 KB)
    __shared__ float    pacc[MB][TPB];      // phase-A partials, [sample][col] (12 KB)
    __shared__ uint32_t keyA[N_SITES], keyB[N_SITES];
    __shared__ float    glds[N_SITES][MB][2];  // precomputed gumbels (4.6 KB)
    __shared__ float    wred[MB][4][2];     // dense partials [sample][group][{a,b}]
    __shared__ int      sPrev[MB];

    // ---- per-thread constants: unit-u gate triples (all 768 threads) ----
    const float kz0 = kern[u];        const float kr0 = kern[u + 256];  const float kn0 = kern[u + 512];
    const float kz1 = kern[768 + u];  const float kr1 = kern[768 + u + 256]; const float kn1 = kern[768 + u + 512];
    const float b0z = bias[u];        const float b0r = bias[u + 256];  const float b0n = bias[u + 512];
    const float b1z = bias[768 + u];  const float b1r = bias[768 + u + 256]; const float b1n = bias[768 + u + 512];
    const float dwa = dw[2 * u];      const float dwb = dw[2 * u + 1];
    const float dba = db[0];          const float dbb = db[1];
    float lgPr = 0.f;                                 // logP (threads 0..3)
    if (t < NHID) hs4[t] = make_float4(0.f, 0.f, 0.f, 0.f);
    if (t < MB) sPrev[t] = -1;
    if (t < N_SITES) {
        uint32_t o0, o1;
        threefry(0u, 42u, 0u, (uint32_t)t, o0, o1);   // foldlike split: counter = n
        keyA[t] = o0; keyB[t] = o1;
    }
    __syncthreads();

    // ---- gumbel precompute: data-independent, hoisted out of the step loop
    //      (same threefry inputs as the in-loop version -> bit-identical) ----
    if (t < N_SITES * MB) {
        const int n = t >> 2, m = t & 3;
        uint32_t o0a, o1a, o0b, o1b;
        const uint32_t fbase = 2u * (uint32_t)(b0 + m);
        threefry(keyA[n], keyB[n], 0u, fbase,      o0a, o1a);
        threefry(keyA[n], keyB[n], 0u, fbase + 1u, o0b, o1b);
        glds[n][m][0] = gumbel_from_bits(o0a ^ o1a);
        glds[n][m][1] = gumbel_from_bits(o0b ^ o1b);
    }
    __syncthreads();

    for (int n = 0; n < N_SITES; ++n) {
        // ---- phase A: one column per thread, single-accumulator ascending
        //      k=0..255 chain (bit-exact). QUAD: one NON-TEMPORAL dwordx4 per
        //      4 k's. The 786 KB/step stream has ~0% L1 hit rate (24x L1
        //      overflow per step); nt skips L1 allocation/eviction churn while
        //      returning identical values in identical order. ----
        float a0 = 0.f, a1 = 0.f, a2 = 0.f, a3 = 0.f;
        if (QUAD) {
            const f32x4* rq = reinterpret_cast<const f32x4*>(rec) + t;
#pragma unroll 8
            for (int g = 0; g < 64; ++g) {
                const f32x4 w = __builtin_nontemporal_load(rq + (size_t)g * TPB);
                float4 h4 = hs4[4 * g + 0];             // broadcast ds_read_b128
                a0 = fmaf(h4.x, w[0], a0);
                a1 = fmaf(h4.y, w[0], a1);
                a2 = fmaf(h4.z, w[0], a2);
                a3 = fmaf(h4.w, w[0], a3);
                h4 = hs4[4 * g + 1];
                a0 = fmaf(h4.x, w[1], a0);
                a1 = fmaf(h4.y, w[1], a1);
                a2 = fmaf(h4.z, w[1], a2);
                a3 = fmaf(h4.w, w[1], a3);
                h4 = hs4[4 * g + 2];
                a0 = fmaf(h4.x, w[2], a0);
                a1 = fmaf(h4.y, w[2], a1);
                a2 = fmaf(h4.z, w[2], a2);
                a3 = fmaf(h4.w, w[2], a3);
                h4 = hs4[4 * g + 3];
                a0 = fmaf(h4.x, w[3], a0);
                a1 = fmaf(h4.y, w[3], a1);
                a2 = fmaf(h4.z, w[3], a2);
                a3 = fmaf(h4.w, w[3], a3);
            }
        } else {
            const float* rp = rec + t;
#pragma unroll 8
            for (int k = 0; k < NHID; ++k) {
                float4 h4 = hs4[k];          // broadcast ds_read_b128
                float w  = rp[0];
                rp += TPB;
                a0 = fmaf(h4.x, w, a0);
                a1 = fmaf(h4.y, w, a1);
                a2 = fmaf(h4.z, w, a2);
                a3 = fmaf(h4.w, w, a3);
            }
        }
        pacc[0][t] = a0; pacc[1][t] = a1; pacc[2][t] = a2; pacc[3][t] = a3;
        __syncthreads();   // B1: pacc ready; all hs4 reads complete

        // ---- phases B+C spread over all 12 waves: 1024 (m,unit) gate tasks.
        //      (R6/R8-verbatim, verified bit-exact) ----
#pragma unroll
        for (int pass = 0; pass < 2; ++pass) {
            const int m = (pass == 0) ? m1 : 3;
            if (pass == 1 && t >= NHID) break;
            float hnew;
            {
#pragma clang fp contract(off)
                const int sp = sPrev[m];
                float xz = (sp == 0) ? kz0 : ((sp == 1) ? kz1 : 0.f);
                float xr = (sp == 0) ? kr0 : ((sp == 1) ? kr1 : 0.f);
                float xh = (sp == 0) ? kn0 : ((sp == 1) ? kn1 : 0.f);
                xz = xz + b0z;  xr = xr + b0r;  xh = xh + b0n;
                const float hz = pacc[m][u]       + b1z;
                const float hr = pacc[m][u + 256] + b1r;
                const float hn = pacc[m][u + 512] + b1n;
                const float z = 1.0f / (1.0f + expf(-(xz + hz)));
                const float r = 1.0f / (1.0f + expf(-(xr + hr)));
                const float rhn = r * hn;
                const float hh = tanhf(xh + rhn);
                const float hold = ((const float*)&hs4[u])[m];   // component m only
                hnew = z * hold + (1.0f - z) * hh;
                ((float*)&hs4[u])[m] = hnew;                     // ds_write_b32
            }
            // dense logits partial (h @ dense_w): butterfly over 64 lanes,
            // group g = u>>6 reproduces the old per-wave partial exactly.
            float va = hnew * dwa;
            float vb = hnew * dwb;
#pragma unroll
            for (int off = 32; off > 0; off >>= 1) {
                va += __shfl_xor(va, off, 64);
                vb += __shfl_xor(vb, off, 64);
            }
            if (lane == 0) { wred[m][u >> 6][0] = va; wred[m][u >> 6][1] = vb; }
        }
        __syncthreads();   // B2: wred + hs4 ready

        // ---- phase D: logits + categorical + logP (4 threads, gumbels precomputed) ----
        if (t < MB) {
            const int m = t;
            // same summation order as the verified kernel: g0+g1+g2+g3, then bias
            float l0 = wred[m][0][0] + wred[m][1][0] + wred[m][2][0] + wred[m][3][0];
            float l1 = wred[m][0][1] + wred[m][1][1] + wred[m][2][1] + wred[m][3][1];
            const float g0 = glds[n][m][0];
            const float g1 = glds[n][m][1];
            {
#pragma clang fp contract(off)
                l0 = l0 + dba;
                l1 = l1 + dbb;
                const float mx = fmaxf(l0, l1);
                const float e0 = expf(l0 - mx), e1 = expf(l1 - mx);
                const float den = e0 + e1;
                const float lp0 = logf(1e-10f + e0 / den);
                const float lp1 = logf(1e-10f + e1 / den);
                const float v0 = g0 + lp0;
                const float v1 = g1 + lp1;
                const int s = (v1 > v0) ? 1 : 0;   // argmax, first-index tie-break
                sPrev[m] = s;
                lgPr = lgPr + (s ? lp1 : lp0);
                out[(size_t)(b0 + m) * N_SITES + n] = (float)s;
            }
        }
        // No third barrier (verified R4-R8): phase D writes only
        // sPrev/out/lgPr(reg); next-step readers of sPrev are behind B1(n+1);
        // wred(n+1)/pacc(n+1) writes are behind B1(n+1) as well.
    }

    if (t < MB) out[(size_t)NSAMP * N_SITES + (b0 + t)] = lgPr;
}

extern "C" void kernel_launch(void* const* d_in, const int* in_sizes, int n_in,
                              void* d_out, int out_size, void* d_ws, size_t ws_size,
                              hipStream_t stream) {
    (void)in_sizes; (void)n_in; (void)out_size;
    const float* kern = (const float*)d_in[0];
    const float* rec  = (const float*)d_in[1];
    const float* bias = (const float*)d_in[2];
    const float* dwp  = (const float*)d_in[3];
    const float* dbp  = (const float*)d_in[4];
    float* out = (float*)d_out;

    const size_t needQ = sizeof(float) * (size_t)NHID * TPB;   // 786 KB
    if (d_ws != nullptr && ws_size >= needQ) {
        float* recQ = (float*)d_ws;
        repack_rec<<<TPB, NHID, 0, stream>>>(rec, recQ);
        rnn_sample_kernel<true><<<NSAMP / MB, TPB, 0, stream>>>(kern, recQ, bias, dwp, dbp, out);
    } else {
        rnn_sample_kernel<false><<<NSAMP / MB, TPB, 0, stream>>>(kern, rec, bias, dwp, dbp, out);
    }
}